// Round 11
// baseline (267.901 us; speedup 1.0000x reference)
//
#include <hip/hip_runtime.h>

typedef unsigned short u16;
typedef __attribute__((ext_vector_type(8))) short short8;
typedef __attribute__((ext_vector_type(8))) unsigned short u16x8;
typedef __attribute__((ext_vector_type(4))) unsigned short u16x4;
typedef __attribute__((ext_vector_type(4))) float f32x4;

#define DEVINL __device__ __forceinline__
#define SGB0 __builtin_amdgcn_sched_barrier(0)

DEVINL u16 f2b(float f) {
    union { float f; unsigned u; } a; a.f = f;
    unsigned r = a.u + 0x7FFFu + ((a.u >> 16) & 1u);
    return (u16)(r >> 16);
}
DEVINL float b2f(u16 h) {
    union { unsigned u; float f; } a; a.u = ((unsigned)h) << 16;
    return a.f;
}

DEVINL void gload16(const void* g, void* l) {
    __builtin_amdgcn_global_load_lds(
        (const __attribute__((address_space(1))) void*)g,
        (__attribute__((address_space(3))) void*)l, 16, 0, 0);
}

// ---------------- mask dtype detection (bool-bytes vs int32) ----------------
__global__ void detect_mask(const unsigned char* __restrict__ m, int nbytes, int* __restrict__ flag) {
    __shared__ int any;
    if (threadIdx.x == 0) any = 0;
    __syncthreads();
    int loc = 0;
    for (int i = threadIdx.x; i < nbytes; i += 256)
        if ((i & 3) && m[i]) loc = 1;
    if (loc) atomicOr(&any, 1);
    __syncthreads();
    if (threadIdx.x == 0) *flag = any;  // 1 => byte/bool layout, 0 => int32 layout
}

// ---------------- f32 -> bf16 copy (vectorized) ----------------
__global__ __launch_bounds__(256) void f32_to_bf16(const float* __restrict__ in, u16* __restrict__ out, int n4) {
    int i = blockIdx.x * 256 + threadIdx.x;
    if (i >= n4) return;
    float4 v = ((const float4*)in)[i];
    u16x4 o = { f2b(v.x), f2b(v.y), f2b(v.z), f2b(v.w) };
    *(u16x4*)(out + (size_t)i * 4) = o;
}

// ---------------- f32 (K x N) -> bf16 transposed (N x K) ----------------
__global__ __launch_bounds__(256) void transpose_bf16(const float* __restrict__ W, u16* __restrict__ WT, int K, int N) {
    __shared__ float tile[32][33];
    int tx = threadIdx.x, ty = threadIdx.y;
    int n0 = blockIdx.x * 32, k0 = blockIdx.y * 32;
#pragma unroll
    for (int i = 0; i < 4; i++)
        tile[ty + i * 8][tx] = W[(size_t)(k0 + ty + i * 8) * N + n0 + tx];
    __syncthreads();
#pragma unroll
    for (int i = 0; i < 4; i++)
        WT[(size_t)(n0 + ty + i * 8) * K + k0 + tx] = f2b(tile[tx][ty + i * 8]);
}

// ---------------- V pre-transpose: qkv V slice -> vtg[bh][d=64][n=1024] bf16 --------------
__global__ __launch_bounds__(256) void transpose_v(const u16* __restrict__ qkv, u16* __restrict__ vtg) {
    __shared__ u16 tile[64][72];  // [n][d], padded rows
    const int bh = blockIdx.x & 63, nt = blockIdx.x >> 6;
    const int b = bh >> 4, h = bh & 15;
    const int t = threadIdx.x;
    const int r = t >> 3, c = (t & 7) << 3;
#pragma unroll
    for (int i = 0; i < 2; i++) {
        int rr = r + i * 32;
        *(u16x8*)&tile[rr][c] =
            *(const u16x8*)&qkv[(size_t)(b * 1024 + nt * 64 + rr) * 3072 + 2048 + h * 64 + c];
    }
    __syncthreads();
#pragma unroll
    for (int i = 0; i < 2; i++) {
        int d = r + i * 32;
        u16x8 o;
#pragma unroll
        for (int e = 0; e < 8; e++) o[e] = tile[c + e][d];
        *(u16x8*)&vtg[(size_t)bh * 65536 + (size_t)d * 1024 + nt * 64 + c] = o;
    }
}

// ---------------- ada path: split-K GEMV partials ----------------
template <int KRLOG2>
__global__ __launch_bounds__(256) void gemv_partial(
    const float* __restrict__ h, const float* __restrict__ w,
    float* __restrict__ part, int N, int K) {
    constexpr int KR = 1 << KRLOG2;
    constexpr int KR4 = KR >> 2;
    __shared__ float hs[4 * KR];
    __shared__ float red[256 * 16];
    const int t = threadIdx.x, wv = t >> 6, l = t & 63;
    const int j4 = blockIdx.x * 256 + l * 4;
    const int kb = blockIdx.y << KRLOG2;
    for (int idx = t; idx < 4 * KR; idx += 256) {
        int b = idx >> KRLOG2, kk = idx & (KR - 1);
        hs[idx] = h[b * K + kb + kk];
    }
    __syncthreads();
    float acc[4][4];
#pragma unroll
    for (int b = 0; b < 4; b++)
#pragma unroll
        for (int c = 0; c < 4; c++) acc[b][c] = 0.f;
    const float* wp = w + (size_t)(kb + wv * KR4) * N + j4;
#pragma unroll
    for (int i = 0; i < KR4; i++) {
        float4 wf = *(const float4*)(wp + (size_t)i * N);
        int kk = wv * KR4 + i;
#pragma unroll
        for (int b = 0; b < 4; b++) {
            float hv = hs[(b << KRLOG2) + kk];
            acc[b][0] += hv * wf.x;
            acc[b][1] += hv * wf.y;
            acc[b][2] += hv * wf.z;
            acc[b][3] += hv * wf.w;
        }
    }
#pragma unroll
    for (int b = 0; b < 4; b++)
#pragma unroll
        for (int c = 0; c < 4; c++)
            red[t * 16 + b * 4 + c] = acc[b][c];
    __syncthreads();
    if (t < 64) {
#pragma unroll
        for (int b = 0; b < 4; b++) {
            float4 s;
            s.x = red[l * 16 + b * 4 + 0] + red[(l + 64) * 16 + b * 4 + 0] + red[(l + 128) * 16 + b * 4 + 0] + red[(l + 192) * 16 + b * 4 + 0];
            s.y = red[l * 16 + b * 4 + 1] + red[(l + 64) * 16 + b * 4 + 1] + red[(l + 128) * 16 + b * 4 + 1] + red[(l + 192) * 16 + b * 4 + 1];
            s.z = red[l * 16 + b * 4 + 2] + red[(l + 64) * 16 + b * 4 + 2] + red[(l + 128) * 16 + b * 4 + 2] + red[(l + 192) * 16 + b * 4 + 2];
            s.w = red[l * 16 + b * 4 + 3] + red[(l + 64) * 16 + b * 4 + 3] + red[(l + 128) * 16 + b * 4 + 3] + red[(l + 192) * 16 + b * 4 + 3];
            *(float4*)&part[(size_t)(blockIdx.y * 4 + b) * N + j4] = s;
        }
    }
}

template <int SILU>
__global__ __launch_bounds__(256) void gemv_reduce(
    const float* __restrict__ part, const float* __restrict__ bias,
    float* __restrict__ out, int N, int NK) {
    int gid = blockIdx.x * 256 + threadIdx.x;
    int b = gid / N, j = gid - b * N;
    float s = bias[j];
    for (int i = 0; i < NK; i++) s += part[(size_t)(i * 4 + b) * N + j];
    if (SILU) s = s / (1.f + __expf(-s));
    out[gid] = s;
}

// ---------------- bf16 GEMM, 256x256 tile, 4-phase fine interleave (T3+T4) --------------
// C[M,N] = A[M,K] @ B^T, B is [N,K]. 512 thr = 8 waves (2M x 4N), per-wave out 128x64.
// LDS 128KB, 2 slots (slot = kt&1). Per K-tile t: 4 phases, quadrant order
// (A0B0)(A0B1)(A1B0)(A1B1), frags held in regs across phases. Staging of tile t+2
// goes into slot t&1's regions AS they are freed: ph1 stages A-rounds 0,2 (read ph0);
// ph2 stages B-rounds 0-3 (read ph0+1); ph3 stages A-rounds 1,3 (read ph2).
// Per-wave issue order per tile: A0,A2,B0,B1,B2,B3,A1,A3 (prologue matches).
// vmcnt ledger (derived & double-checked; counts are OUTSTANDING loads allowed):
//   ph0: need A0,A2,B0-3(t) landed -> after them: A1,A3(t)[2] + tile(t+1)'s 8 = 10
//        (last tile: 2).
//   ph2: need A1,A3(t) landed -> after them: t+1's 8 + ph1-of-t stages [2 if stg] =
//        10 (stg) / 8 (no stg) / 0 (last).
//   Never vmcnt(0) mid-loop. Entry barrier AFTER vmcnt => block-wide landing.
// EPI: 0 = write bf16 raw (split-K via Cb/Cb2); 2 = +bias, GELU(erf), write bf16
template <int EPI>
__global__ __launch_bounds__(512) void gemm256(
    const u16* __restrict__ A, const u16* __restrict__ B, const float* __restrict__ bias,
    u16* __restrict__ Cb, u16* __restrict__ Cb2, int M, int N, int lda, int Ksub) {
    __shared__ u16 As[2][256 * 64];
    __shared__ u16 Bs[2][256 * 64];
    const int t = threadIdx.x;
    const int w = t >> 6, l = t & 63;
    const int l15 = l & 15, lg = l >> 4;
    const int nTN = N >> 8;
    const int ntiles = (M >> 8) * nTN;
    const int sk = blockIdx.x / ntiles;
    int tb = blockIdx.x - sk * ntiles;
    tb = (tb & 7) * (ntiles >> 3) + (tb >> 3);  // bijective XCD swizzle (ntiles % 8 == 0)
    const int tm = tb / nTN, tn = tb - tm * nTN;
    const int row0 = tm << 8, col0 = tn << 8;
    const int wr = (w >> 2) << 7, wc = (w & 3) << 6;
    const int k_begin = sk * Ksub;

    const int rA = t >> 3;                       // 0..63
    const int cswz = ((t & 7) ^ (rA & 7)) << 3;  // pre-swizzled global source (rule #21)
    const u16* gA = A + (size_t)(row0 + rA) * lda + cswz + k_begin;
    const u16* gB = B + (size_t)(col0 + rA) * lda + cswz + k_begin;
    const int rsw = l15 & 7;

    f32x4 acc[8][4];
#pragma unroll
    for (int i = 0; i < 8; i++)
#pragma unroll
        for (int j = 0; j < 4; j++) acc[i][j] = (f32x4){0.f, 0.f, 0.f, 0.f};

    const int nkt = Ksub >> 6;

    // stage one 64-row round (8KB) of A or B for K-tile kt
    auto SA = [&](int kt, int j) {
        gload16(gA + (size_t)j * 64 * lda + (kt << 6), As[kt & 1] + j * 4096 + w * 512);
    };
    auto SB = [&](int kt, int j) {
        gload16(gB + (size_t)j * 64 * lda + (kt << 6), Bs[kt & 1] + j * 4096 + w * 512);
    };

    // prologue: tiles 0,1 staged in the canonical per-tile order A0,A2,B0..B3,A1,A3
    SA(0, 0); SA(0, 2); SB(0, 0); SB(0, 1); SB(0, 2); SB(0, 3); SA(0, 1); SA(0, 3);
    SA(1, 0); SA(1, 2); SB(1, 0); SB(1, 1); SB(1, 2); SB(1, 3); SA(1, 1); SA(1, 3);

    for (int kt = 0; kt < nkt; ++kt) {
        const int cur = kt & 1;
        const bool last = (kt == nkt - 1);
        const bool stg = (kt + 2 < nkt);

        // ================= phase 0: quadrant A0 x B0 =================
        if (last) asm volatile("s_waitcnt vmcnt(2)" ::: "memory");
        else      asm volatile("s_waitcnt vmcnt(10)" ::: "memory");
        SGB0;
        __builtin_amdgcn_s_barrier();
        SGB0;
        short8 a0[2][4], b0[2][2];
#pragma unroll
        for (int ks = 0; ks < 2; ks++) {
            const int chunk = (((ks << 2) + lg) ^ rsw) << 3;
#pragma unroll
            for (int mi = 0; mi < 4; mi++)
                a0[ks][mi] = *(const short8*)&As[cur][((wr + mi * 16 + l15) << 6) + chunk];
#pragma unroll
            for (int ni = 0; ni < 2; ni++)
                b0[ks][ni] = *(const short8*)&Bs[cur][((wc + ni * 16 + l15) << 6) + chunk];
        }
        asm volatile("s_waitcnt lgkmcnt(0)" ::: "memory");
        SGB0;
        __builtin_amdgcn_s_setprio(1);
#pragma unroll
        for (int ks = 0; ks < 2; ks++)
#pragma unroll
            for (int mi = 0; mi < 4; mi++)
#pragma unroll
                for (int ni = 0; ni < 2; ni++)
                    acc[mi][ni] = __builtin_amdgcn_mfma_f32_16x16x32_bf16(a0[ks][mi], b0[ks][ni], acc[mi][ni], 0, 0, 0);
        __builtin_amdgcn_s_setprio(0);

        // ================= phase 1: quadrant A0 x B1 =================
        SGB0;
        __builtin_amdgcn_s_barrier();   // A-rounds 0,2 of slot cur now free block-wide
        SGB0;
        short8 b1[2][2];
#pragma unroll
        for (int ks = 0; ks < 2; ks++) {
            const int chunk = (((ks << 2) + lg) ^ rsw) << 3;
#pragma unroll
            for (int ni = 0; ni < 2; ni++)
                b1[ks][ni] = *(const short8*)&Bs[cur][((wc + (ni + 2) * 16 + l15) << 6) + chunk];
        }
        if (stg) { SA(kt + 2, 0); SA(kt + 2, 2); }
        asm volatile("s_waitcnt lgkmcnt(0)" ::: "memory");
        SGB0;
        __builtin_amdgcn_s_setprio(1);
#pragma unroll
        for (int ks = 0; ks < 2; ks++)
#pragma unroll
            for (int mi = 0; mi < 4; mi++)
#pragma unroll
                for (int ni = 0; ni < 2; ni++)
                    acc[mi][ni + 2] = __builtin_amdgcn_mfma_f32_16x16x32_bf16(a0[ks][mi], b1[ks][ni], acc[mi][ni + 2], 0, 0, 0);
        __builtin_amdgcn_s_setprio(0);

        // ================= phase 2: quadrant A1 x B0 =================
        if (last)     asm volatile("s_waitcnt vmcnt(0)" ::: "memory");
        else if (stg) asm volatile("s_waitcnt vmcnt(10)" ::: "memory");
        else          asm volatile("s_waitcnt vmcnt(8)" ::: "memory");
        SGB0;
        __builtin_amdgcn_s_barrier();   // B-rounds of slot cur now free block-wide
        SGB0;
        short8 a1[2][4];
#pragma unroll
        for (int ks = 0; ks < 2; ks++) {
            const int chunk = (((ks << 2) + lg) ^ rsw) << 3;
#pragma unroll
            for (int mi = 0; mi < 4; mi++)
                a1[ks][mi] = *(const short8*)&As[cur][((wr + (mi + 4) * 16 + l15) << 6) + chunk];
        }
        if (stg) { SB(kt + 2, 0); SB(kt + 2, 1); SB(kt + 2, 2); SB(kt + 2, 3); }
        asm volatile("s_waitcnt lgkmcnt(0)" ::: "memory");
        SGB0;
        __builtin_amdgcn_s_setprio(1);
#pragma unroll
        for (int ks = 0; ks < 2; ks++)
#pragma unroll
            for (int mi = 0; mi < 4; mi++)
#pragma unroll
                for (int ni = 0; ni < 2; ni++)
                    acc[mi + 4][ni] = __builtin_amdgcn_mfma_f32_16x16x32_bf16(a1[ks][mi], b0[ks][ni], acc[mi + 4][ni], 0, 0, 0);
        __builtin_amdgcn_s_setprio(0);

        // ================= phase 3: quadrant A1 x B1 =================
        SGB0;
        __builtin_amdgcn_s_barrier();   // A-rounds 1,3 of slot cur now free block-wide
        SGB0;
        if (stg) { SA(kt + 2, 1); SA(kt + 2, 3); }
        __builtin_amdgcn_s_setprio(1);
#pragma unroll
        for (int ks = 0; ks < 2; ks++)
#pragma unroll
            for (int mi = 0; mi < 4; mi++)
#pragma unroll
                for (int ni = 0; ni < 2; ni++)
                    acc[mi + 4][ni + 2] = __builtin_amdgcn_mfma_f32_16x16x32_bf16(a1[ks][mi], b1[ks][ni], acc[mi + 4][ni + 2], 0, 0, 0);
        __builtin_amdgcn_s_setprio(0);
    }

    const size_t MNsz = (size_t)M * N;
    u16* dst = (sk < 2) ? Cb + (size_t)sk * MNsz : Cb2 + (size_t)(sk - 2) * MNsz;
#pragma unroll
    for (int mi = 0; mi < 8; mi++) {
#pragma unroll
        for (int ni = 0; ni < 4; ni++) {
#pragma unroll
            for (int j = 0; j < 4; j++) {
                int r = row0 + wr + mi * 16 + (lg << 2) + j;
                int c = col0 + wc + ni * 16 + l15;
                float v = acc[mi][ni][j];
                if (EPI == 0) {
                    dst[(size_t)r * N + c] = f2b(v);
                } else {
                    float vv = v + bias[c];
                    float g = 0.5f * vv * (1.f + erff(vv * 0.70710678118f));
                    dst[(size_t)r * N + c] = f2b(g);
                }
            }
        }
    }
}

// ---------------- flash attention: swapped-QK^T, lane-local softmax, defer-max ----------------
__global__ __launch_bounds__(256) void attn_kernel(
    const u16* __restrict__ qkv, const u16* __restrict__ vtg,
    const unsigned char* __restrict__ maskb,
    const int* __restrict__ flagp, u16* __restrict__ out) {
    __shared__ u16 Qs[64 * 64];
    __shared__ u16 Ks[64 * 64];
    __shared__ u16 Vt[64 * 64];
    __shared__ u16 Ps[64 * 64];
    __shared__ float maskf[64];
    __shared__ float alpha_lds[64];
    __shared__ float lst_lds[64];

    int bi = (int)blockIdx.x;
    bi = (bi & 7) * 128 + (bi >> 3);
    const int qt = bi & 15, h = (bi >> 4) & 15, b = bi >> 8;
    const int t = threadIdx.x, w = t >> 6, l = t & 63;
    const int l15 = l & 15, lg = l >> 4;
    const int rsw = l15 & 7;
    const int flag = *flagp;
    const int q0 = qt << 6;
    const int bh = b * 16 + h;

    const int sr = t >> 3, sc = t & 7;
#pragma unroll
    for (int i = 0; i < 2; i++) {
        int r = sr + i * 32;
        u16x8 v = *(const u16x8*)&qkv[(size_t)(b * 1024 + q0 + r) * 3072 + h * 64 + sc * 8];
        u16x8 o;
#pragma unroll
        for (int e = 0; e < 8; e++) o[e] = f2b(b2f(v[e]) * 0.125f);
        *(u16x8*)&Qs[r * 64 + ((sc ^ (r & 7)) << 3)] = o;
    }

    f32x4 O[4];
#pragma unroll
    for (int nd = 0; nd < 4; nd++) O[nd] = (f32x4){0.f, 0.f, 0.f, 0.f};
    float mst = -1e30f, lst = 0.f;

    u16x8 kreg[2], vreg[2];
    float mnext;
    {
#pragma unroll
        for (int i = 0; i < 2; i++) {
            kreg[i] = *(const u16x8*)&qkv[(size_t)(b * 1024 + sr + i * 32) * 3072 + h * 64 + 1024 + sc * 8];
            vreg[i] = *(const u16x8*)&vtg[(size_t)bh * 65536 + (size_t)(sr + i * 32) * 1024 + sc * 8];
        }
        int gi = b * 1024 + (t & 63);
        bool ms = flag ? (maskb[gi] != 0) : (((const int*)maskb)[gi] != 0);
        mnext = ms ? 1.f : 0.f;
    }

    for (int kt = 0; kt < 16; kt++) {
        __syncthreads();
#pragma unroll
        for (int i = 0; i < 2; i++) {
            int r = sr + i * 32;
            *(u16x8*)&Ks[r * 64 + ((sc ^ (r & 7)) << 3)] = kreg[i];
            *(u16x8*)&Vt[r * 64 + ((sc ^ (r & 7)) << 3)] = vreg[i];
        }
        if (t < 64) maskf[t] = mnext;
        __syncthreads();
        if (kt < 15) {
            const int kn = (kt + 1) << 6;
#pragma unroll
            for (int i = 0; i < 2; i++) {
                kreg[i] = *(const u16x8*)&qkv[(size_t)(b * 1024 + kn + sr + i * 32) * 3072 + h * 64 + 1024 + sc * 8];
                vreg[i] = *(const u16x8*)&vtg[(size_t)bh * 65536 + (size_t)(sr + i * 32) * 1024 + kn + sc * 8];
            }
            int gi = b * 1024 + kn + (t & 63);
            bool ms = flag ? (maskb[gi] != 0) : (((const int*)maskb)[gi] != 0);
            mnext = ms ? 1.f : 0.f;
        }

        f32x4 S[4];
#pragma unroll
        for (int mi = 0; mi < 4; mi++) S[mi] = (f32x4){0.f, 0.f, 0.f, 0.f};
        __builtin_amdgcn_s_setprio(1);
#pragma unroll
        for (int ks = 0; ks < 2; ks++) {
            const int chunk = (((ks << 2) + lg) ^ rsw) << 3;
            short8 bq = *(const short8*)&Qs[(w * 16 + l15) * 64 + chunk];
#pragma unroll
            for (int mi = 0; mi < 4; mi++) {
                short8 ak = *(const short8*)&Ks[(mi * 16 + l15) * 64 + chunk];
                S[mi] = __builtin_amdgcn_mfma_f32_16x16x32_bf16(ak, bq, S[mi], 0, 0, 0);
            }
        }
        __builtin_amdgcn_s_setprio(0);

        float pm = -1e30f;
#pragma unroll
        for (int mi = 0; mi < 4; mi++) {
            f32x4 mk = *(const f32x4*)&maskf[mi * 16 + (lg << 2)];
#pragma unroll
            for (int j = 0; j < 4; j++) {
                float xv = (mk[j] > 0.f) ? S[mi][j] : -1e30f;
                S[mi][j] = xv;
                pm = fmaxf(pm, xv);
            }
        }
        pm = fmaxf(pm, __shfl_xor(pm, 16));
        pm = fmaxf(pm, __shfl_xor(pm, 32));

        bool skip = __all(pm <= mst + 8.f);
        float alpha = 1.f;
        if (!skip) {
            float mn = fmaxf(mst, pm);
            alpha = __expf(mst - mn);
            mst = mn;
        }

        float psum = 0.f;
        const int prow = w * 16 + l15;
#pragma unroll
        for (int mi = 0; mi < 4; mi++) {
            f32x4 mk = *(const f32x4*)&maskf[mi * 16 + (lg << 2)];
            u16x4 v4;
#pragma unroll
            for (int j = 0; j < 4; j++) {
                float p = __expf(S[mi][j] - mst) * mk[j];
                psum += p;
                v4[j] = f2b(p);
            }
            int ch = ((mi * 2 + (lg >> 1)) ^ rsw);
            *(u16x4*)&Ps[prow * 64 + (ch << 3) + ((lg & 1) << 2)] = v4;
        }
        psum += __shfl_xor(psum, 16);
        psum += __shfl_xor(psum, 32);
        lst = lst * alpha + psum;

        if (!skip) {
            if (lg == 0) alpha_lds[w * 16 + l15] = alpha;
            f32x4 af = *(const f32x4*)&alpha_lds[w * 16 + (lg << 2)];
#pragma unroll
            for (int nd = 0; nd < 4; nd++)
#pragma unroll
                for (int j = 0; j < 4; j++) O[nd][j] *= af[j];
        }

        __builtin_amdgcn_s_setprio(1);
#pragma unroll
        for (int ks = 0; ks < 2; ks++) {
            const int chunk = (((ks << 2) + lg) ^ rsw) << 3;
            short8 pa = *(const short8*)&Ps[(w * 16 + l15) * 64 + chunk];
#pragma unroll
            for (int nd = 0; nd < 4; nd++) {
                short8 bv = *(const short8*)&Vt[(nd * 16 + l15) * 64 + chunk];
                O[nd] = __builtin_amdgcn_mfma_f32_16x16x32_bf16(pa, bv, O[nd], 0, 0, 0);
            }
        }
        __builtin_amdgcn_s_setprio(0);
    }

    if (lg == 0) lst_lds[w * 16 + l15] = lst;
    f32x4 lf = *(const f32x4*)&lst_lds[w * 16 + (lg << 2)];
#pragma unroll
    for (int nd = 0; nd < 4; nd++)
#pragma unroll
        for (int j = 0; j < 4; j++) {
            int r = b * 1024 + q0 + w * 16 + (lg << 2) + j;
            int c = h * 64 + nd * 16 + l15;
            out[(size_t)r * 1024 + c] = f2b(O[nd][j] / lf[j]);
        }
}

// ---------------- LN(sum of 4 bf16 partials + bias) * (1+scale) + shift, gated, + resid ----
__global__ __launch_bounds__(256) void ln_mod_res4(
    const u16* __restrict__ s0, const u16* __restrict__ s1, const float* __restrict__ bias,
    const float* __restrict__ resid, const float* __restrict__ ada, int oS, int oC, int oG,
    float* __restrict__ outf, u16* __restrict__ outb) {
    __shared__ float red[8];
    const int row = blockIdx.x, t = threadIdx.x, b = row >> 10;
    const float4 bv = ((const float4*)bias)[t];
    const size_t MN = 1ull << 22;  // 4096*1024
    const u16* p0 = s0 + (size_t)row * 1024 + t * 4;
    const u16* p1 = s1 + (size_t)row * 1024 + t * 4;
    u16x4 a0 = *(const u16x4*)p0;
    u16x4 a1 = *(const u16x4*)(p0 + MN);
    u16x4 a2 = *(const u16x4*)p1;
    u16x4 a3 = *(const u16x4*)(p1 + MN);
    float4 v;
    v.x = (b2f(a0[0]) + b2f(a1[0])) + (b2f(a2[0]) + b2f(a3[0])) + bv.x;
    v.y = (b2f(a0[1]) + b2f(a1[1])) + (b2f(a2[1]) + b2f(a3[1])) + bv.y;
    v.z = (b2f(a0[2]) + b2f(a1[2])) + (b2f(a2[2]) + b2f(a3[2])) + bv.z;
    v.w = (b2f(a0[3]) + b2f(a1[3])) + (b2f(a2[3]) + b2f(a3[3])) + bv.w;
    float s = v.x + v.y + v.z + v.w;
    float q = v.x * v.x + v.y * v.y + v.z * v.z + v.w * v.w;
#pragma unroll
    for (int off = 32; off >= 1; off >>= 1) {
        s += __shfl_down(s, off);
        q += __shfl_down(q, off);
    }
    if ((t & 63) == 0) { red[(t >> 6) * 2] = s; red[(t >> 6) * 2 + 1] = q; }
    __syncthreads();
    float sum = red[0] + red[2] + red[4] + red[6];
    float sq = red[1] + red[3] + red[5] + red[7];
    float mu = sum * (1.f / 1024.f);
    float var = sq * (1.f / 1024.f) - mu * mu;
    float rinv = rsqrtf(var + 1e-5f);
    const float* ad = ada + b * 6144;
    const float4 rv = ((const float4*)(resid + (size_t)row * 1024))[t];
    const float4 sc = ((const float4*)(ad + oC))[t];
    const float4 sh = ((const float4*)(ad + oS))[t];
    const float4 gt = ((const float4*)(ad + oG))[t];
    float4 o;
    o.x = rv.x + gt.x * ((v.x - mu) * rinv * (1.f + sc.x) + sh.x);
    o.y = rv.y + gt.y * ((v.y - mu) * rinv * (1.f + sc.y) + sh.y);
    o.z = rv.z + gt.z * ((v.z - mu) * rinv * (1.f + sc.z) + sh.z);
    o.w = rv.w + gt.w * ((v.w - mu) * rinv * (1.f + sc.w) + sh.w);
    ((float4*)(outf + (size_t)row * 1024))[t] = o;
    if (outb) {
        u16x4 ob = { f2b(o.x), f2b(o.y), f2b(o.z), f2b(o.w) };
        *(u16x4*)(outb + (size_t)row * 1024 + t * 4) = ob;
    }
}

extern "C" void kernel_launch(void* const* d_in, const int* in_sizes, int n_in,
                              void* d_out, int out_size, void* d_ws, size_t ws_size,
                              hipStream_t stream) {
    (void)in_sizes; (void)n_in; (void)out_size; (void)ws_size;
    const float* x = (const float*)d_in[0];
    const float* cvec = (const float*)d_in[1];
    const unsigned char* maskb = (const unsigned char*)d_in[2];
    const float* qkv_w = (const float*)d_in[3];
    const float* proj_w = (const float*)d_in[4];
    const float* proj_b = (const float*)d_in[5];
    const float* fc1_w = (const float*)d_in[6];
    const float* fc1_b = (const float*)d_in[7];
    const float* fc2_w = (const float*)d_in[8];
    const float* fc2_b = (const float*)d_in[9];
    const float* ada1_w = (const float*)d_in[10];
    const float* ada1_b = (const float*)d_in[11];
    const float* ada2_w = (const float*)d_in[12];
    const float* ada2_b = (const float*)d_in[13];
    float* outp = (float*)d_out;

    char* ws = (char*)d_ws;
    size_t off = 0;
    auto nxt = [&](size_t bytes) { size_t r = off; off += (bytes + 255) & ~(size_t)255; return r; };
    // [0, 16.78MB): qkvwT + projwT + fc1wT -- dead after fc1 gemm; reused as fc2 partials 2,3
    u16* qkvwT  = (u16*)(ws + nxt(3072ull * 1024 * 2));
    u16* projwT = (u16*)(ws + nxt(1024ull * 1024 * 2));
    u16* fc1wT  = (u16*)(ws + nxt(4096ull * 1024 * 2));
    u16* fc2wT  = (u16*)(ws + nxt(1024ull * 4096 * 2));
    float* adah = (float*)(ws + nxt(4ull * 1024 * 4));
    float* ada  = (float*)(ws + nxt(4ull * 6144 * 4));
    float* part1 = (float*)(ws + nxt(32ull * 4 * 1024 * 4));
    float* part2 = (float*)(ws + nxt(8ull * 4 * 6144 * 4));
    int* flag   = (int*)(ws + nxt(256));
    u16* xbf = (u16*)(ws + nxt(4096ull * 1024 * 2));
    u16* attn_buf = xbf;
    // regC (33.55MB): qkvbf (25.2MB, live through attn) -> proj partials (4x bf16) -> hbuf
    char* regC = ws + nxt(2ull * 4096 * 1024 * 4);
    u16* qkvbf = (u16*)regC;
    u16* projpart = (u16*)regC;      // 4 partials of 4096*1024 bf16
    u16* hbuf = (u16*)regC;
    float* y1 = (float*)(ws + nxt(4096ull * 1024 * 4));
    u16* y1b = (u16*)(ws + nxt(4096ull * 1024 * 2));
    u16* fc2part = (u16*)(ws + nxt(2ull * 4096 * 1024 * 2));
    u16* vtg = fc2part;          // vtg live qkv-gemm..attn; fc2 partials 0,1 written after
    u16* fc2partB = (u16*)ws;    // partials 2,3 overlay dead qkvwT/projwT/fc1wT (16.78MB exact)
    const size_t MN = 4096ull * 1024;

    detect_mask<<<1, 256, 0, stream>>>(maskb, 4096, flag);
    f32_to_bf16<<<4096, 256, 0, stream>>>(x, xbf, 1048576);
    transpose_bf16<<<dim3(96, 32), dim3(32, 8), 0, stream>>>(qkv_w, qkvwT, 1024, 3072);
    transpose_bf16<<<dim3(32, 32), dim3(32, 8), 0, stream>>>(proj_w, projwT, 1024, 1024);
    transpose_bf16<<<dim3(128, 32), dim3(32, 8), 0, stream>>>(fc1_w, fc1wT, 1024, 4096);
    transpose_bf16<<<dim3(32, 128), dim3(32, 8), 0, stream>>>(fc2_w, fc2wT, 4096, 1024);

    gemv_partial<5><<<dim3(4, 32), 256, 0, stream>>>(cvec, ada1_w, part1, 1024, 1024);
    gemv_reduce<1><<<16, 256, 0, stream>>>(part1, ada1_b, adah, 1024, 32);
    gemv_partial<7><<<dim3(24, 8), 256, 0, stream>>>(adah, ada2_w, part2, 6144, 1024);
    gemv_reduce<0><<<96, 256, 0, stream>>>(part2, ada2_b, ada, 6144, 8);

    // qkv = x @ qkv_w -> bf16 (256^2 tiles: 16x12 = 192 blocks)
    gemm256<0><<<192, 512, 0, stream>>>(xbf, qkvwT, nullptr, qkvbf, nullptr, 4096, 3072, 1024, 1024);
    transpose_v<<<1024, 256, 0, stream>>>(qkvbf, vtg);
    attn_kernel<<<1024, 256, 0, stream>>>(qkvbf, vtg, maskb, flag, attn_buf);
    // proj: 256^2 split-K=4 (64 tiles x 4 = 256 blocks) -> 4 bf16 partials in regC
    gemm256<0><<<256, 512, 0, stream>>>(attn_buf, projwT, nullptr, projpart, projpart + 2 * MN,
                                        4096, 1024, 1024, 256);
    // y1 = x + gate_msa * modulate(LN(p0+p1+p2+p3+proj_b))
    ln_mod_res4<<<4096, 256, 0, stream>>>(projpart, projpart + 2 * MN, proj_b,
                                          x, ada, 0, 1024, 2048, y1, y1b);
    // fc1: 256^2 (16x16 = 256 blocks), GELU epilogue
    gemm256<2><<<256, 512, 0, stream>>>(y1b, fc1wT, fc1_b, hbuf, nullptr, 4096, 4096, 1024, 1024);
    // fc2: 256^2 split-K=4 (64 tiles x 4 = 256 blocks) -> 4 bf16 partials
    gemm256<0><<<256, 512, 0, stream>>>(hbuf, fc2wT, nullptr, fc2part, fc2partB, 4096, 1024, 4096, 1024);
    // out = y1 + gate_mlp * modulate(LN(q0+q1+q2+q3+fc2_b))
    ln_mod_res4<<<4096, 256, 0, stream>>>(fc2part, fc2partB, fc2_b,
                                          y1, ada, 3072, 4096, 5120, outp, nullptr);
}

// Round 12
// 255.356 us; speedup vs baseline: 1.0491x; 1.0491x over previous
//
#include <hip/hip_runtime.h>

typedef unsigned short u16;
typedef __attribute__((ext_vector_type(8))) short short8;
typedef __attribute__((ext_vector_type(8))) unsigned short u16x8;
typedef __attribute__((ext_vector_type(4))) unsigned short u16x4;
typedef __attribute__((ext_vector_type(4))) float f32x4;

#define DEVINL __device__ __forceinline__
#define SGB0 __builtin_amdgcn_sched_barrier(0)

DEVINL u16 f2b(float f) {
    union { float f; unsigned u; } a; a.f = f;
    unsigned r = a.u + 0x7FFFu + ((a.u >> 16) & 1u);
    return (u16)(r >> 16);
}
DEVINL float b2f(u16 h) {
    union { unsigned u; float f; } a; a.u = ((unsigned)h) << 16;
    return a.f;
}

DEVINL void gload16(const void* g, void* l) {
    __builtin_amdgcn_global_load_lds(
        (const __attribute__((address_space(1))) void*)g,
        (__attribute__((address_space(3))) void*)l, 16, 0, 0);
}

// ---------------- f32 -> bf16 copy + mask dtype detection (fused) ----------------
// blocks [0, n4/256): convert; block n4/256: detect mask layout (bool-bytes vs int32)
__global__ __launch_bounds__(256) void convert_and_mask(
    const float* __restrict__ in, u16* __restrict__ out, int n4,
    const unsigned char* __restrict__ m, int nbytes, int* __restrict__ flag) {
    int i = blockIdx.x * 256 + threadIdx.x;
    if (blockIdx.x == gridDim.x - 1) {
        __shared__ int any;
        if (threadIdx.x == 0) any = 0;
        __syncthreads();
        int loc = 0;
        for (int k = threadIdx.x; k < nbytes; k += 256)
            if ((k & 3) && m[k]) loc = 1;
        if (loc) atomicOr(&any, 1);
        __syncthreads();
        if (threadIdx.x == 0) *flag = any;  // 1 => byte/bool layout, 0 => int32 layout
        return;
    }
    if (i >= n4) return;
    float4 v = ((const float4*)in)[i];
    u16x4 o = { f2b(v.x), f2b(v.y), f2b(v.z), f2b(v.w) };
    *(u16x4*)(out + (size_t)i * 4) = o;
}

// ---------------- all 4 weight transposes fused: f32 (K x N) -> bf16 (N x K) ----------
// grid partition: qkv 3072 | proj 1024 | fc1 4096 | fc2 4096 = 12288 blocks, dim (32,8)
__global__ __launch_bounds__(256) void transpose_all(
    const float* __restrict__ qkvw, const float* __restrict__ projw,
    const float* __restrict__ fc1w, const float* __restrict__ fc2w,
    u16* __restrict__ qkvT, u16* __restrict__ projT,
    u16* __restrict__ fc1T, u16* __restrict__ fc2T) {
    __shared__ float tile[32][33];
    int bid = blockIdx.x;
    const float* W; u16* WT; int K, N, bx, by;
    if (bid < 3072)      { W = qkvw;  WT = qkvT;  K = 1024; N = 3072; bx = bid % 96;  by = bid / 96; }
    else if (bid < 4096) { int b = bid - 3072; W = projw; WT = projT; K = 1024; N = 1024; bx = b % 32;  by = b / 32; }
    else if (bid < 8192) { int b = bid - 4096; W = fc1w;  WT = fc1T;  K = 1024; N = 4096; bx = b % 128; by = b / 128; }
    else                 { int b = bid - 8192; W = fc2w;  WT = fc2T;  K = 4096; N = 1024; bx = b % 32;  by = b / 32; }
    int tx = threadIdx.x, ty = threadIdx.y;
    int n0 = bx * 32, k0 = by * 32;
#pragma unroll
    for (int i = 0; i < 4; i++)
        tile[ty + i * 8][tx] = W[(size_t)(k0 + ty + i * 8) * N + n0 + tx];
    __syncthreads();
#pragma unroll
    for (int i = 0; i < 4; i++)
        WT[(size_t)(n0 + ty + i * 8) * K + k0 + tx] = f2b(tile[tx][ty + i * 8]);
}

// ---------------- V pre-transpose: qkv V slice -> vtg[bh][d=64][n=1024] bf16 --------------
__global__ __launch_bounds__(256) void transpose_v(const u16* __restrict__ qkv, u16* __restrict__ vtg) {
    __shared__ u16 tile[64][72];  // [n][d], padded rows
    const int bh = blockIdx.x & 63, nt = blockIdx.x >> 6;
    const int b = bh >> 4, h = bh & 15;
    const int t = threadIdx.x;
    const int r = t >> 3, c = (t & 7) << 3;
#pragma unroll
    for (int i = 0; i < 2; i++) {
        int rr = r + i * 32;
        *(u16x8*)&tile[rr][c] =
            *(const u16x8*)&qkv[(size_t)(b * 1024 + nt * 64 + rr) * 3072 + 2048 + h * 64 + c];
    }
    __syncthreads();
#pragma unroll
    for (int i = 0; i < 2; i++) {
        int d = r + i * 32;
        u16x8 o;
#pragma unroll
        for (int e = 0; e < 8; e++) o[e] = tile[c + e][d];
        *(u16x8*)&vtg[(size_t)bh * 65536 + (size_t)d * 1024 + nt * 64 + c] = o;
    }
}

// ---------------- ada path: split-K GEMV partials ----------------
template <int KRLOG2>
__global__ __launch_bounds__(256) void gemv_partial(
    const float* __restrict__ h, const float* __restrict__ w,
    float* __restrict__ part, int N, int K) {
    constexpr int KR = 1 << KRLOG2;
    constexpr int KR4 = KR >> 2;
    __shared__ float hs[4 * KR];
    __shared__ float red[256 * 16];
    const int t = threadIdx.x, wv = t >> 6, l = t & 63;
    const int j4 = blockIdx.x * 256 + l * 4;
    const int kb = blockIdx.y << KRLOG2;
    for (int idx = t; idx < 4 * KR; idx += 256) {
        int b = idx >> KRLOG2, kk = idx & (KR - 1);
        hs[idx] = h[b * K + kb + kk];
    }
    __syncthreads();
    float acc[4][4];
#pragma unroll
    for (int b = 0; b < 4; b++)
#pragma unroll
        for (int c = 0; c < 4; c++) acc[b][c] = 0.f;
    const float* wp = w + (size_t)(kb + wv * KR4) * N + j4;
#pragma unroll
    for (int i = 0; i < KR4; i++) {
        float4 wf = *(const float4*)(wp + (size_t)i * N);
        int kk = wv * KR4 + i;
#pragma unroll
        for (int b = 0; b < 4; b++) {
            float hv = hs[(b << KRLOG2) + kk];
            acc[b][0] += hv * wf.x;
            acc[b][1] += hv * wf.y;
            acc[b][2] += hv * wf.z;
            acc[b][3] += hv * wf.w;
        }
    }
#pragma unroll
    for (int b = 0; b < 4; b++)
#pragma unroll
        for (int c = 0; c < 4; c++)
            red[t * 16 + b * 4 + c] = acc[b][c];
    __syncthreads();
    if (t < 64) {
#pragma unroll
        for (int b = 0; b < 4; b++) {
            float4 s;
            s.x = red[l * 16 + b * 4 + 0] + red[(l + 64) * 16 + b * 4 + 0] + red[(l + 128) * 16 + b * 4 + 0] + red[(l + 192) * 16 + b * 4 + 0];
            s.y = red[l * 16 + b * 4 + 1] + red[(l + 64) * 16 + b * 4 + 1] + red[(l + 128) * 16 + b * 4 + 1] + red[(l + 192) * 16 + b * 4 + 1];
            s.z = red[l * 16 + b * 4 + 2] + red[(l + 64) * 16 + b * 4 + 2] + red[(l + 128) * 16 + b * 4 + 2] + red[(l + 192) * 16 + b * 4 + 2];
            s.w = red[l * 16 + b * 4 + 3] + red[(l + 64) * 16 + b * 4 + 3] + red[(l + 128) * 16 + b * 4 + 3] + red[(l + 192) * 16 + b * 4 + 3];
            *(float4*)&part[(size_t)(blockIdx.y * 4 + b) * N + j4] = s;
        }
    }
}

template <int SILU>
__global__ __launch_bounds__(256) void gemv_reduce(
    const float* __restrict__ part, const float* __restrict__ bias,
    float* __restrict__ out, int N, int NK) {
    int gid = blockIdx.x * 256 + threadIdx.x;
    int b = gid / N, j = gid - b * N;
    float s = bias[j];
    for (int i = 0; i < NK; i++) s += part[(size_t)(i * 4 + b) * N + j];
    if (SILU) s = s / (1.f + __expf(-s));
    out[gid] = s;
}

// ---------------- bf16 GEMM, 256x256 tile, counted-vmcnt 2-deep pipeline ----------------
// (R10-verified version: 16x16x32 MFMA, 0 bank conflicts, 264.7us config. FROZEN.)
template <int EPI>
__global__ __launch_bounds__(512) void gemm256(
    const u16* __restrict__ A, const u16* __restrict__ B, const float* __restrict__ bias,
    u16* __restrict__ Cb, u16* __restrict__ Cb2, int M, int N, int lda, int Ksub) {
    __shared__ u16 As[2][256 * 64];
    __shared__ u16 Bs[2][256 * 64];
    const int t = threadIdx.x;
    const int w = t >> 6, l = t & 63;
    const int l15 = l & 15, lg = l >> 4;
    const int nTN = N >> 8;
    const int ntiles = (M >> 8) * nTN;
    const int sk = blockIdx.x / ntiles;
    int tb = blockIdx.x - sk * ntiles;
    tb = (tb & 7) * (ntiles >> 3) + (tb >> 3);  // bijective XCD swizzle (ntiles % 8 == 0)
    const int tm = tb / nTN, tn = tb - tm * nTN;
    const int row0 = tm << 8, col0 = tn << 8;
    const int wr = (w >> 2) << 7, wc = (w & 3) << 6;
    const int k_begin = sk * Ksub;

    const int rA = t >> 3;                       // 0..63
    const int cswz = ((t & 7) ^ (rA & 7)) << 3;  // pre-swizzled global source (rule #21)
    const u16* gA = A + (size_t)(row0 + rA) * lda + cswz + k_begin;
    const u16* gB = B + (size_t)(col0 + rA) * lda + cswz + k_begin;
    const int rsw = l15 & 7;

    f32x4 acc[8][4];
#pragma unroll
    for (int i = 0; i < 8; i++)
#pragma unroll
        for (int j = 0; j < 4; j++) acc[i][j] = (f32x4){0.f, 0.f, 0.f, 0.f};

    const int nkt = Ksub >> 6;

    auto STAGE = [&](int kt, int s) {
        const int k0 = kt << 6;
#pragma unroll
        for (int j = 0; j < 4; j++)
            gload16(gA + (size_t)j * 64 * lda + k0, As[s] + j * 4096 + w * 512);
#pragma unroll
        for (int j = 0; j < 4; j++)
            gload16(gB + (size_t)j * 64 * lda + k0, Bs[s] + j * 4096 + w * 512);
    };

    // prologue: stage tiles 0,1 (16 loads); wait tile0 (oldest 8) landed
    STAGE(0, 0);
    STAGE(1, 1);
    asm volatile("s_waitcnt vmcnt(8)" ::: "memory");
    SGB0;
    __builtin_amdgcn_s_barrier();
    SGB0;

    for (int it = 0; it < nkt; ++it) {
        const int cur = it & 1;
        // ---- sub-phase ks=0: read 12 frags, MFMA 32 ----
        short8 af0[8], bf0[4];
        {
            const int chunk = (lg ^ rsw) << 3;
#pragma unroll
            for (int mi = 0; mi < 8; mi++)
                af0[mi] = *(const short8*)&As[cur][((wr + mi * 16 + l15) << 6) + chunk];
#pragma unroll
            for (int ni = 0; ni < 4; ni++)
                bf0[ni] = *(const short8*)&Bs[cur][((wc + ni * 16 + l15) << 6) + chunk];
        }
        __builtin_amdgcn_s_setprio(1);
#pragma unroll
        for (int mi = 0; mi < 8; mi++)
#pragma unroll
            for (int ni = 0; ni < 4; ni++)
                acc[mi][ni] = __builtin_amdgcn_mfma_f32_16x16x32_bf16(af0[mi], bf0[ni], acc[mi][ni], 0, 0, 0);
        __builtin_amdgcn_s_setprio(0);
        // ---- sub-phase ks=1: read 12 frags; slot[cur] fully read after these ----
        short8 af1[8], bf1[4];
        {
            const int chunk = ((4 + lg) ^ rsw) << 3;
#pragma unroll
            for (int mi = 0; mi < 8; mi++)
                af1[mi] = *(const short8*)&As[cur][((wr + mi * 16 + l15) << 6) + chunk];
#pragma unroll
            for (int ni = 0; ni < 4; ni++)
                bf1[ni] = *(const short8*)&Bs[cur][((wc + ni * 16 + l15) << 6) + chunk];
        }
        asm volatile("s_waitcnt lgkmcnt(0)" ::: "memory");
        SGB0;
        __builtin_amdgcn_s_barrier();   // block-wide: slot[cur] fully read
        SGB0;
        if (it + 2 < nkt) STAGE(it + 2, cur);   // overwrite slot[cur] (async)
        __builtin_amdgcn_s_setprio(1);
#pragma unroll
        for (int mi = 0; mi < 8; mi++)
#pragma unroll
            for (int ni = 0; ni < 4; ni++)
                acc[mi][ni] = __builtin_amdgcn_mfma_f32_16x16x32_bf16(af1[mi], bf1[ni], acc[mi][ni], 0, 0, 0);
        __builtin_amdgcn_s_setprio(0);
        if (it + 1 < nkt) {
            // tile t+1 (issued last iter) must be landed; t+2 keeps flying
            if (it + 2 < nkt) asm volatile("s_waitcnt vmcnt(8)" ::: "memory");
            else              asm volatile("s_waitcnt vmcnt(0)" ::: "memory");
            SGB0;
            __builtin_amdgcn_s_barrier();
            SGB0;
        }
    }

    const size_t MNsz = (size_t)M * N;
    u16* dst = (sk < 2) ? Cb + (size_t)sk * MNsz : Cb2 + (size_t)(sk - 2) * MNsz;
#pragma unroll
    for (int mi = 0; mi < 8; mi++) {
#pragma unroll
        for (int ni = 0; ni < 4; ni++) {
#pragma unroll
            for (int j = 0; j < 4; j++) {
                int r = row0 + wr + mi * 16 + (lg << 2) + j;
                int c = col0 + wc + ni * 16 + l15;
                float v = acc[mi][ni][j];
                if (EPI == 0) {
                    dst[(size_t)r * N + c] = f2b(v);
                } else {
                    float vv = v + bias[c];
                    float g = 0.5f * vv * (1.f + erff(vv * 0.70710678118f));
                    dst[(size_t)r * N + c] = f2b(g);
                }
            }
        }
    }
}

// ---------------- flash attention: swapped-QK^T, lane-local softmax, defer-max ----------------
__global__ __launch_bounds__(256) void attn_kernel(
    const u16* __restrict__ qkv, const u16* __restrict__ vtg,
    const unsigned char* __restrict__ maskb,
    const int* __restrict__ flagp, u16* __restrict__ out) {
    __shared__ u16 Qs[64 * 64];
    __shared__ u16 Ks[64 * 64];
    __shared__ u16 Vt[64 * 64];
    __shared__ u16 Ps[64 * 64];
    __shared__ float maskf[64];
    __shared__ float alpha_lds[64];
    __shared__ float lst_lds[64];

    int bi = (int)blockIdx.x;
    bi = (bi & 7) * 128 + (bi >> 3);
    const int qt = bi & 15, h = (bi >> 4) & 15, b = bi >> 8;
    const int t = threadIdx.x, w = t >> 6, l = t & 63;
    const int l15 = l & 15, lg = l >> 4;
    const int rsw = l15 & 7;
    const int flag = *flagp;
    const int q0 = qt << 6;
    const int bh = b * 16 + h;

    const int sr = t >> 3, sc = t & 7;
#pragma unroll
    for (int i = 0; i < 2; i++) {
        int r = sr + i * 32;
        u16x8 v = *(const u16x8*)&qkv[(size_t)(b * 1024 + q0 + r) * 3072 + h * 64 + sc * 8];
        u16x8 o;
#pragma unroll
        for (int e = 0; e < 8; e++) o[e] = f2b(b2f(v[e]) * 0.125f);
        *(u16x8*)&Qs[r * 64 + ((sc ^ (r & 7)) << 3)] = o;
    }

    f32x4 O[4];
#pragma unroll
    for (int nd = 0; nd < 4; nd++) O[nd] = (f32x4){0.f, 0.f, 0.f, 0.f};
    float mst = -1e30f, lst = 0.f;

    u16x8 kreg[2], vreg[2];
    float mnext;
    {
#pragma unroll
        for (int i = 0; i < 2; i++) {
            kreg[i] = *(const u16x8*)&qkv[(size_t)(b * 1024 + sr + i * 32) * 3072 + h * 64 + 1024 + sc * 8];
            vreg[i] = *(const u16x8*)&vtg[(size_t)bh * 65536 + (size_t)(sr + i * 32) * 1024 + sc * 8];
        }
        int gi = b * 1024 + (t & 63);
        bool ms = flag ? (maskb[gi] != 0) : (((const int*)maskb)[gi] != 0);
        mnext = ms ? 1.f : 0.f;
    }

    for (int kt = 0; kt < 16; kt++) {
        __syncthreads();
#pragma unroll
        for (int i = 0; i < 2; i++) {
            int r = sr + i * 32;
            *(u16x8*)&Ks[r * 64 + ((sc ^ (r & 7)) << 3)] = kreg[i];
            *(u16x8*)&Vt[r * 64 + ((sc ^ (r & 7)) << 3)] = vreg[i];
        }
        if (t < 64) maskf[t] = mnext;
        __syncthreads();
        if (kt < 15) {
            const int kn = (kt + 1) << 6;
#pragma unroll
            for (int i = 0; i < 2; i++) {
                kreg[i] = *(const u16x8*)&qkv[(size_t)(b * 1024 + kn + sr + i * 32) * 3072 + h * 64 + 1024 + sc * 8];
                vreg[i] = *(const u16x8*)&vtg[(size_t)bh * 65536 + (size_t)(sr + i * 32) * 1024 + kn + sc * 8];
            }
            int gi = b * 1024 + kn + (t & 63);
            bool ms = flag ? (maskb[gi] != 0) : (((const int*)maskb)[gi] != 0);
            mnext = ms ? 1.f : 0.f;
        }

        f32x4 S[4];
#pragma unroll
        for (int mi = 0; mi < 4; mi++) S[mi] = (f32x4){0.f, 0.f, 0.f, 0.f};
        __builtin_amdgcn_s_setprio(1);
#pragma unroll
        for (int ks = 0; ks < 2; ks++) {
            const int chunk = (((ks << 2) + lg) ^ rsw) << 3;
            short8 bq = *(const short8*)&Qs[(w * 16 + l15) * 64 + chunk];
#pragma unroll
            for (int mi = 0; mi < 4; mi++) {
                short8 ak = *(const short8*)&Ks[(mi * 16 + l15) * 64 + chunk];
                S[mi] = __builtin_amdgcn_mfma_f32_16x16x32_bf16(ak, bq, S[mi], 0, 0, 0);
            }
        }
        __builtin_amdgcn_s_setprio(0);

        float pm = -1e30f;
#pragma unroll
        for (int mi = 0; mi < 4; mi++) {
            f32x4 mk = *(const f32x4*)&maskf[mi * 16 + (lg << 2)];
#pragma unroll
            for (int j = 0; j < 4; j++) {
                float xv = (mk[j] > 0.f) ? S[mi][j] : -1e30f;
                S[mi][j] = xv;
                pm = fmaxf(pm, xv);
            }
        }
        pm = fmaxf(pm, __shfl_xor(pm, 16));
        pm = fmaxf(pm, __shfl_xor(pm, 32));

        bool skip = __all(pm <= mst + 8.f);
        float alpha = 1.f;
        if (!skip) {
            float mn = fmaxf(mst, pm);
            alpha = __expf(mst - mn);
            mst = mn;
        }

        float psum = 0.f;
        const int prow = w * 16 + l15;
#pragma unroll
        for (int mi = 0; mi < 4; mi++) {
            f32x4 mk = *(const f32x4*)&maskf[mi * 16 + (lg << 2)];
            u16x4 v4;
#pragma unroll
            for (int j = 0; j < 4; j++) {
                float p = __expf(S[mi][j] - mst) * mk[j];
                psum += p;
                v4[j] = f2b(p);
            }
            int ch = ((mi * 2 + (lg >> 1)) ^ rsw);
            *(u16x4*)&Ps[prow * 64 + (ch << 3) + ((lg & 1) << 2)] = v4;
        }
        psum += __shfl_xor(psum, 16);
        psum += __shfl_xor(psum, 32);
        lst = lst * alpha + psum;

        if (!skip) {
            if (lg == 0) alpha_lds[w * 16 + l15] = alpha;
            f32x4 af = *(const f32x4*)&alpha_lds[w * 16 + (lg << 2)];
#pragma unroll
            for (int nd = 0; nd < 4; nd++)
#pragma unroll
                for (int j = 0; j < 4; j++) O[nd][j] *= af[j];
        }

        __builtin_amdgcn_s_setprio(1);
#pragma unroll
        for (int ks = 0; ks < 2; ks++) {
            const int chunk = (((ks << 2) + lg) ^ rsw) << 3;
            short8 pa = *(const short8*)&Ps[(w * 16 + l15) * 64 + chunk];
#pragma unroll
            for (int nd = 0; nd < 4; nd++) {
                short8 bv = *(const short8*)&Vt[(nd * 16 + l15) * 64 + chunk];
                O[nd] = __builtin_amdgcn_mfma_f32_16x16x32_bf16(pa, bv, O[nd], 0, 0, 0);
            }
        }
        __builtin_amdgcn_s_setprio(0);
    }

    if (lg == 0) lst_lds[w * 16 + l15] = lst;
    f32x4 lf = *(const f32x4*)&lst_lds[w * 16 + (lg << 2)];
#pragma unroll
    for (int nd = 0; nd < 4; nd++)
#pragma unroll
        for (int j = 0; j < 4; j++) {
            int r = b * 1024 + q0 + w * 16 + (lg << 2) + j;
            int c = h * 64 + nd * 16 + l15;
            out[(size_t)r * 1024 + c] = f2b(O[nd][j] / lf[j]);
        }
}

// ---------------- LN(sum of 4 bf16 partials + bias) * (1+scale) + shift, gated, + resid ----
__global__ __launch_bounds__(256) void ln_mod_res4(
    const u16* __restrict__ s0, const u16* __restrict__ s1, const float* __restrict__ bias,
    const float* __restrict__ resid, const float* __restrict__ ada, int oS, int oC, int oG,
    float* __restrict__ outf, u16* __restrict__ outb) {
    __shared__ float red[8];
    const int row = blockIdx.x, t = threadIdx.x, b = row >> 10;
    const float4 bv = ((const float4*)bias)[t];
    const size_t MN = 1ull << 22;  // 4096*1024
    const u16* p0 = s0 + (size_t)row * 1024 + t * 4;
    const u16* p1 = s1 + (size_t)row * 1024 + t * 4;
    u16x4 a0 = *(const u16x4*)p0;
    u16x4 a1 = *(const u16x4*)(p0 + MN);
    u16x4 a2 = *(const u16x4*)p1;
    u16x4 a3 = *(const u16x4*)(p1 + MN);
    float4 v;
    v.x = (b2f(a0[0]) + b2f(a1[0])) + (b2f(a2[0]) + b2f(a3[0])) + bv.x;
    v.y = (b2f(a0[1]) + b2f(a1[1])) + (b2f(a2[1]) + b2f(a3[1])) + bv.y;
    v.z = (b2f(a0[2]) + b2f(a1[2])) + (b2f(a2[2]) + b2f(a3[2])) + bv.z;
    v.w = (b2f(a0[3]) + b2f(a1[3])) + (b2f(a2[3]) + b2f(a3[3])) + bv.w;
    float s = v.x + v.y + v.z + v.w;
    float q = v.x * v.x + v.y * v.y + v.z * v.z + v.w * v.w;
#pragma unroll
    for (int off = 32; off >= 1; off >>= 1) {
        s += __shfl_down(s, off);
        q += __shfl_down(q, off);
    }
    if ((t & 63) == 0) { red[(t >> 6) * 2] = s; red[(t >> 6) * 2 + 1] = q; }
    __syncthreads();
    float sum = red[0] + red[2] + red[4] + red[6];
    float sq = red[1] + red[3] + red[5] + red[7];
    float mu = sum * (1.f / 1024.f);
    float var = sq * (1.f / 1024.f) - mu * mu;
    float rinv = rsqrtf(var + 1e-5f);
    const float* ad = ada + b * 6144;
    const float4 rv = ((const float4*)(resid + (size_t)row * 1024))[t];
    const float4 sc = ((const float4*)(ad + oC))[t];
    const float4 sh = ((const float4*)(ad + oS))[t];
    const float4 gt = ((const float4*)(ad + oG))[t];
    float4 o;
    o.x = rv.x + gt.x * ((v.x - mu) * rinv * (1.f + sc.x) + sh.x);
    o.y = rv.y + gt.y * ((v.y - mu) * rinv * (1.f + sc.y) + sh.y);
    o.z = rv.z + gt.z * ((v.z - mu) * rinv * (1.f + sc.z) + sh.z);
    o.w = rv.w + gt.w * ((v.w - mu) * rinv * (1.f + sc.w) + sh.w);
    ((float4*)(outf + (size_t)row * 1024))[t] = o;
    if (outb) {
        u16x4 ob = { f2b(o.x), f2b(o.y), f2b(o.z), f2b(o.w) };
        *(u16x4*)(outb + (size_t)row * 1024 + t * 4) = ob;
    }
}

extern "C" void kernel_launch(void* const* d_in, const int* in_sizes, int n_in,
                              void* d_out, int out_size, void* d_ws, size_t ws_size,
                              hipStream_t stream) {
    (void)in_sizes; (void)n_in; (void)out_size; (void)ws_size;
    const float* x = (const float*)d_in[0];
    const float* cvec = (const float*)d_in[1];
    const unsigned char* maskb = (const unsigned char*)d_in[2];
    const float* qkv_w = (const float*)d_in[3];
    const float* proj_w = (const float*)d_in[4];
    const float* proj_b = (const float*)d_in[5];
    const float* fc1_w = (const float*)d_in[6];
    const float* fc1_b = (const float*)d_in[7];
    const float* fc2_w = (const float*)d_in[8];
    const float* fc2_b = (const float*)d_in[9];
    const float* ada1_w = (const float*)d_in[10];
    const float* ada1_b = (const float*)d_in[11];
    const float* ada2_w = (const float*)d_in[12];
    const float* ada2_b = (const float*)d_in[13];
    float* outp = (float*)d_out;

    char* ws = (char*)d_ws;
    size_t off = 0;
    auto nxt = [&](size_t bytes) { size_t r = off; off += (bytes + 255) & ~(size_t)255; return r; };
    // [0, 16.78MB): qkvwT + projwT + fc1wT -- dead after fc1 gemm; reused as fc2 partials 2,3
    u16* qkvwT  = (u16*)(ws + nxt(3072ull * 1024 * 2));
    u16* projwT = (u16*)(ws + nxt(1024ull * 1024 * 2));
    u16* fc1wT  = (u16*)(ws + nxt(4096ull * 1024 * 2));
    u16* fc2wT  = (u16*)(ws + nxt(1024ull * 4096 * 2));
    float* adah = (float*)(ws + nxt(4ull * 1024 * 4));
    float* ada  = (float*)(ws + nxt(4ull * 6144 * 4));
    float* part1 = (float*)(ws + nxt(32ull * 4 * 1024 * 4));
    float* part2 = (float*)(ws + nxt(8ull * 4 * 6144 * 4));
    int* flag   = (int*)(ws + nxt(256));
    u16* xbf = (u16*)(ws + nxt(4096ull * 1024 * 2));
    u16* attn_buf = xbf;
    // regC (33.55MB): qkvbf (25.2MB, live through attn) -> proj partials (4x bf16) -> hbuf
    char* regC = ws + nxt(2ull * 4096 * 1024 * 4);
    u16* qkvbf = (u16*)regC;
    u16* projpart = (u16*)regC;      // 4 partials of 4096*1024 bf16
    u16* hbuf = (u16*)regC;
    float* y1 = (float*)(ws + nxt(4096ull * 1024 * 4));
    u16* y1b = (u16*)(ws + nxt(4096ull * 1024 * 2));
    u16* fc2part = (u16*)(ws + nxt(2ull * 4096 * 1024 * 2));
    u16* vtg = fc2part;          // vtg live qkv-gemm..attn; fc2 partials 0,1 written after
    u16* fc2partB = (u16*)ws;    // partials 2,3 overlay dead qkvwT/projwT/fc1wT (16.78MB exact)
    const size_t MN = 4096ull * 1024;

    // fused prep: x->bf16 + mask-layout detect (last block), all 4 weight transposes
    convert_and_mask<<<4097, 256, 0, stream>>>(x, xbf, 1048576, maskb, 4096, flag);
    transpose_all<<<12288, dim3(32, 8), 0, stream>>>(qkv_w, proj_w, fc1_w, fc2_w,
                                                     qkvwT, projwT, fc1wT, fc2wT);

    gemv_partial<5><<<dim3(4, 32), 256, 0, stream>>>(cvec, ada1_w, part1, 1024, 1024);
    gemv_reduce<1><<<16, 256, 0, stream>>>(part1, ada1_b, adah, 1024, 32);
    gemv_partial<7><<<dim3(24, 8), 256, 0, stream>>>(adah, ada2_w, part2, 6144, 1024);
    gemv_reduce<0><<<96, 256, 0, stream>>>(part2, ada2_b, ada, 6144, 8);

    // qkv = x @ qkv_w -> bf16 (256^2 tiles: 16x12 = 192 blocks)
    gemm256<0><<<192, 512, 0, stream>>>(xbf, qkvwT, nullptr, qkvbf, nullptr, 4096, 3072, 1024, 1024);
    transpose_v<<<1024, 256, 0, stream>>>(qkvbf, vtg);
    attn_kernel<<<1024, 256, 0, stream>>>(qkvbf, vtg, maskb, flag, attn_buf);
    // proj: 256^2 split-K=4 (64 tiles x 4 = 256 blocks) -> 4 bf16 partials in regC
    gemm256<0><<<256, 512, 0, stream>>>(attn_buf, projwT, nullptr, projpart, projpart + 2 * MN,
                                        4096, 1024, 1024, 256);
    // y1 = x + gate_msa * modulate(LN(p0+p1+p2+p3+proj_b))
    ln_mod_res4<<<4096, 256, 0, stream>>>(projpart, projpart + 2 * MN, proj_b,
                                          x, ada, 0, 1024, 2048, y1, y1b);
    // fc1: 256^2 (16x16 = 256 blocks), GELU epilogue
    gemm256<2><<<256, 512, 0, stream>>>(y1b, fc1wT, fc1_b, hbuf, nullptr, 4096, 4096, 1024, 1024);
    // fc2: 256^2 split-K=4 (64 tiles x 4 = 256 blocks) -> 4 bf16 partials
    gemm256<0><<<256, 512, 0, stream>>>(hbuf, fc2wT, nullptr, fc2part, fc2partB, 4096, 1024, 4096, 1024);
    // out = y1 + gate_mlp * modulate(LN(q0+q1+q2+q3+fc2_b))
    ln_mod_res4<<<4096, 256, 0, stream>>>(fc2part, fc2partB, fc2_b,
                                          y1, ada, 3072, 4096, 5120, outp, nullptr);
}